// Round 10
// baseline (425.040 us; speedup 1.0000x reference)
//
#include <hip/hip_runtime.h>
#include <hip/hip_bf16.h>

#define N_GRAPHS 64
#define IN_FEATS 64
#define HIDDEN 32
#define OUT_DIM 2

#define NB 512        // dst-range buckets
#define PCH 8192      // edges per partition block (LDS stage = 32 KB packed)
#define GCH 256       // nodes per gsum chunk

#define G_HIST 256
#define G_GSUM 391    // ceil(100000/256)
#define G_LIN1 391

__device__ __forceinline__ float bf2f(unsigned short u) {
    unsigned int x = ((unsigned int)u) << 16;
    float f;
    __builtin_memcpy(&f, &x, 4);
    return f;
}

__device__ __forceinline__ unsigned short f2bf(float f) {
    __hip_bfloat16 h = __float2bfloat16(f);   // RNE
    unsigned short u;
    __builtin_memcpy(&u, &h, 2);
    return u;
}

// ---------------- K0: init (zero accumulators, graph bounds) ----------------

__global__ __launch_bounds__(256) void k_init(const int* __restrict__ gids, int n,
                                              int* __restrict__ gstart,
                                              float* __restrict__ ge,
                                              int* __restrict__ gcount,
                                              int* __restrict__ done) {
    int tid = threadIdx.x;
    for (int i = tid; i < N_GRAPHS * IN_FEATS; i += 256) ge[i] = 0.f;
    for (int i = tid; i < NB; i += 256) gcount[i] = 0;
    if (tid < 2) done[tid] = 0;   // [0]=hist, [1]=gsum
    if (tid <= N_GRAPHS) {
        int g = tid;
        int lo = 0, hi = n;
        while (lo < hi) {
            int mid = (lo + hi) >> 1;
            if (gids[mid] < g) lo = mid + 1; else hi = mid;
        }
        gstart[g] = lo;
    }
}

// ---------------- K1: fused front-end: hist(+scan tail) | gsum(+pred tail) | lin1 ----

__global__ __launch_bounds__(256) void k_front(
        // hist/scan
        const int* __restrict__ dst, int E, int nb_sz,
        int* __restrict__ gcount, int* __restrict__ gbase, int* __restrict__ gcur,
        // gsum/pred
        const float* __restrict__ nf, const int* __restrict__ gids,
        const int* __restrict__ gstart, float* __restrict__ ge, int N,
        const float* __restrict__ Wl, const float* __restrict__ bl,
        float* __restrict__ out,
        // lin1
        const float* __restrict__ W1, unsigned int* __restrict__ tA,
        int* __restrict__ done) {
    __shared__ int lc[NB];
    __shared__ int sA[NB], sB[NB];
    __shared__ float4 red[256];
    __shared__ float w1s[IN_FEATS * HIDDEN];
    int tid = threadIdx.x;
    int bx = blockIdx.x;

    if (bx < G_HIST) {
        // ---------- histogram region ----------
        for (int k = tid; k < NB; k += 256) lc[k] = 0;
        __syncthreads();
        int stride = G_HIST * 256;
        for (int i = bx * 256 + tid; i < E; i += stride)
            atomicAdd(&lc[dst[i] / nb_sz], 1);
        __syncthreads();
        for (int k = tid; k < NB; k += 256)
            if (lc[k]) atomicAdd(&gcount[k], lc[k]);

        // last-finishing hist block performs the 512-entry exclusive scan
        __threadfence();
        __shared__ int isLast;
        if (tid == 0) isLast = (atomicAdd(&done[0], 1) == G_HIST - 1) ? 1 : 0;
        __syncthreads();
        if (isLast) {
            __threadfence();
            int c0 = gcount[tid], c1 = gcount[tid + 256];
            sA[tid] = c0; sA[tid + 256] = c1;
            __syncthreads();
            int* a = sA; int* bb = sB;
            for (int off = 1; off < NB; off <<= 1) {
                for (int k = tid; k < NB; k += 256) {
                    int v = a[k];
                    if (k >= off) v += a[k - off];
                    bb[k] = v;
                }
                __syncthreads();
                int* t_ = a; a = bb; bb = t_;
            }
            int e0 = a[tid] - c0, e1 = a[tid + 256] - c1;
            gbase[tid] = e0;       gbase[tid + 256] = e1;
            gcur[tid] = e0;        gcur[tid + 256] = e1;
            if (tid == 0) gbase[NB] = E;
        }
    } else if (bx < G_HIST + G_GSUM) {
        // ---------- per-graph feature-sum region ----------
        int bid = bx - G_HIST;
        int c0 = bid * GCH;
        int c1 = c0 + GCH; if (c1 > N) c1 = N;
        int ng = tid >> 4;    // node group 0..15
        int f4 = tid & 15;    // float4 column
        if (c0 < N) {
            int gfirst = gids[c0];
            int glast  = gids[c1 - 1];
            for (int g = gfirst; g <= glast; g++) {
                int s = gstart[g];     if (s < c0) s = c0;
                int e = gstart[g + 1]; if (e > c1) e = c1;
                float4 acc = make_float4(0.f, 0.f, 0.f, 0.f);
                for (int i = s + ng; i < e; i += 16) {
                    float4 v = *reinterpret_cast<const float4*>(nf + (long long)i * IN_FEATS + f4 * 4);
                    acc.x += v.x; acc.y += v.y; acc.z += v.z; acc.w += v.w;
                }
                red[tid] = acc;
                __syncthreads();
                for (int off = 8; off > 0; off >>= 1) {
                    if (ng < off) {
                        float4 o = red[(ng + off) * 16 + f4];
                        float4 m = red[tid];
                        m.x += o.x; m.y += o.y; m.z += o.z; m.w += o.w;
                        red[tid] = m;
                    }
                    __syncthreads();
                }
                if (ng == 0 && e > s) {
                    float4 m = red[f4];
                    atomicAdd(&ge[g * IN_FEATS + f4 * 4 + 0], m.x);
                    atomicAdd(&ge[g * IN_FEATS + f4 * 4 + 1], m.y);
                    atomicAdd(&ge[g * IN_FEATS + f4 * 4 + 2], m.z);
                    atomicAdd(&ge[g * IN_FEATS + f4 * 4 + 3], m.w);
                }
                __syncthreads();
            }
        }
        // last-finishing gsum block computes the prediction
        __threadfence();
        __shared__ int isLastG;
        if (tid == 0) isLastG = (atomicAdd(&done[1], 1) == G_GSUM - 1) ? 1 : 0;
        __syncthreads();
        if (isLastG) {
            __threadfence();
            int g = tid;
            if (g < N_GRAPHS) {
                float cnt = (float)(gstart[g + 1] - gstart[g]);
                float inv = 1.f / fmaxf(cnt, 1.0f);
                float acc = 0.f;
                for (int k = 0; k < IN_FEATS; k++)
                    acc += ge[g * IN_FEATS + k] * Wl[k];
                acc = acc * inv + bl[0];
                out[g] = 1.f / (1.f + expf(-acc));
            }
        }
    } else {
        // ---------- lin1 region: t = nf @ W1 -> bf16 [N,32] ----------
        int bid = bx - G_HIST - G_GSUM;
        for (int i = tid; i < IN_FEATS * HIDDEN; i += 256) w1s[i] = W1[i];
        __syncthreads();
        int row = bid * 256 + tid;
        if (row >= N) return;
        float a[IN_FEATS];
        const float4* r4 = reinterpret_cast<const float4*>(nf + (long long)row * IN_FEATS);
        #pragma unroll
        for (int v = 0; v < IN_FEATS / 4; v++) {
            float4 q = r4[v];
            a[v * 4 + 0] = q.x; a[v * 4 + 1] = q.y; a[v * 4 + 2] = q.z; a[v * 4 + 3] = q.w;
        }
        float acc[HIDDEN];
        #pragma unroll
        for (int f = 0; f < HIDDEN; f++) acc[f] = 0.f;
        for (int k = 0; k < IN_FEATS; k++) {
            float av = a[k];
            #pragma unroll
            for (int f = 0; f < HIDDEN; f++) acc[f] += av * w1s[k * HIDDEN + f];
        }
        unsigned int packed[HIDDEN / 2];
        #pragma unroll
        for (int f = 0; f < HIDDEN / 2; f++)
            packed[f] = (unsigned int)f2bf(acc[2 * f]) | ((unsigned int)f2bf(acc[2 * f + 1]) << 16);
        uint4* o = reinterpret_cast<uint4*>(tA + (long long)row * 16);
        #pragma unroll
        for (int v = 0; v < 4; v++)
            o[v] = make_uint4(packed[v * 4], packed[v * 4 + 1], packed[v * 4 + 2], packed[v * 4 + 3]);
    }
}

// ---------------- partition + per-bucket counting sort ----------------

// packed pair: (src << 8) | (dst - bucket_base); nb_sz<=256 so local dst fits 8 bits
__global__ __launch_bounds__(256) void k_partition(const int* __restrict__ src,
                                                   const int* __restrict__ dst,
                                                   int* __restrict__ gcur,
                                                   unsigned int* __restrict__ pairs,
                                                   int E, int nb_sz) {
    __shared__ unsigned int stage[PCH];
    __shared__ int sA[NB], sB[NB], ofs[NB + 1], cur[NB], rbase[NB];
    int tid = threadIdx.x;
    int e0 = blockIdx.x * PCH;
    int m = E - e0; if (m > PCH) m = PCH;

    for (int k = tid; k < NB; k += 256) sA[k] = 0;
    __syncthreads();
    for (int i = tid; i < m; i += 256)
        atomicAdd(&sA[dst[e0 + i] / nb_sz], 1);
    __syncthreads();
    int c0 = sA[tid], c1 = sA[tid + 256];
    int* a = sA; int* bb = sB;
    for (int off = 1; off < NB; off <<= 1) {
        for (int k = tid; k < NB; k += 256) {
            int v = a[k];
            if (k >= off) v += a[k - off];
            bb[k] = v;
        }
        __syncthreads();
        int* t_ = a; a = bb; bb = t_;
    }
    int x0 = a[tid] - c0, x1 = a[tid + 256] - c1;
    ofs[tid] = x0;       ofs[tid + 256] = x1;
    cur[tid] = x0;       cur[tid + 256] = x1;
    if (tid == 0) ofs[NB] = m;
    __syncthreads();
    for (int i = tid; i < m; i += 256) {
        int d = dst[e0 + i];
        int s = src[e0 + i];
        int b = d / nb_sz;
        int p = atomicAdd(&cur[b], 1);
        stage[p] = ((unsigned)s << 8) | (unsigned)(d - b * nb_sz);
    }
    __syncthreads();
    for (int k = tid; k < NB; k += 256) {
        int cnt = ofs[k + 1] - ofs[k];
        rbase[k] = cnt > 0 ? atomicAdd(&gcur[k], cnt) : 0;
    }
    __syncthreads();
    for (int i = tid; i < m; i += 256) {
        int lo = 0, hi = NB;
        while (hi - lo > 1) {
            int mid = (lo + hi) >> 1;
            if (ofs[mid] <= i) lo = mid; else hi = mid;
        }
        pairs[rbase[lo] + (i - ofs[lo])] = stage[i];
    }
}

__global__ __launch_bounds__(256) void k_csr_local(const unsigned int* __restrict__ pairs,
                                                   const int* __restrict__ gbase,
                                                   int* __restrict__ csr,
                                                   int* __restrict__ ptr,
                                                   int N, int nb_sz) {
    int b = blockIdx.x;
    int n0 = b * nb_sz;
    if (n0 >= N) return;
    int n1 = n0 + nb_sz; if (n1 > N) n1 = N;
    int nn = n1 - n0;

    __shared__ int cnt[256], scn[256], cur[256];
    int tid = threadIdx.x;
    cnt[tid] = 0;
    __syncthreads();
    int s = gbase[b], e = gbase[b + 1];
    for (int i = s + tid; i < e; i += 256)
        atomicAdd(&cnt[pairs[i] & 0xFFu], 1);
    __syncthreads();
    int c = cnt[tid];
    scn[tid] = c;
    __syncthreads();
    for (int off = 1; off < 256; off <<= 1) {
        int mine = scn[tid];
        int add = (tid >= off) ? scn[tid - off] : 0;
        __syncthreads();
        scn[tid] = mine + add;
        __syncthreads();
    }
    cur[tid] = scn[tid] - c;                      // exclusive prefix
    if (tid < nn) ptr[n0 + tid] = s + scn[tid];   // end offset
    __syncthreads();
    for (int i = s + tid; i < e; i += 256) {
        unsigned int p = pairs[i];
        int pos = atomicAdd(&cur[p & 0xFFu], 1);
        csr[s + pos] = (int)(p >> 8);
    }
}

// ---------------- fused gather + linear (R8 structure: 16 lanes/node) ----------------

__global__ __launch_bounds__(256) void k_gather_lin2(const unsigned int* __restrict__ tin,
                                                     const int* __restrict__ csr,
                                                     const int* __restrict__ ptr,
                                                     const float* __restrict__ b,
                                                     const float* __restrict__ W,
                                                     unsigned int* __restrict__ tout,
                                                     int n) {
    __shared__ float w[HIDDEN * HIDDEN];
    __shared__ float bs[HIDDEN];
    __shared__ float rows[16][HIDDEN + 1];   // +1 pad
    int tid = threadIdx.x;
    for (int i = tid; i < HIDDEN * HIDDEN; i += 256) w[i] = W[i];
    if (tid < HIDDEN) bs[tid] = b[tid];
    __syncthreads();

    int g = tid >> 4;        // node group 0..15
    int l = tid & 15;        // lane owns feats 2l, 2l+1
    int node = blockIdx.x * 16 + g;
    bool act = node < n;

    if (act) {
        int start = node ? ptr[node - 1] : 0;
        int end = ptr[node];
        float a0 = 0.f, a1 = 0.f;
        int j = start;
        for (; j + 3 < end; j += 4) {
            int s0 = csr[j], s1 = csr[j + 1], s2 = csr[j + 2], s3 = csr[j + 3];
            unsigned int u0 = tin[s0 * 16 + l];
            unsigned int u1 = tin[s1 * 16 + l];
            unsigned int u2 = tin[s2 * 16 + l];
            unsigned int u3 = tin[s3 * 16 + l];
            a0 += bf2f((unsigned short)(u0 & 0xffffu)) + bf2f((unsigned short)(u1 & 0xffffu));
            a1 += bf2f((unsigned short)(u0 >> 16))     + bf2f((unsigned short)(u1 >> 16));
            a0 += bf2f((unsigned short)(u2 & 0xffffu)) + bf2f((unsigned short)(u3 & 0xffffu));
            a1 += bf2f((unsigned short)(u2 >> 16))     + bf2f((unsigned short)(u3 >> 16));
        }
        for (; j < end; j++) {
            unsigned int u = tin[csr[j] * 16 + l];
            a0 += bf2f((unsigned short)(u & 0xffffu));
            a1 += bf2f((unsigned short)(u >> 16));
        }
        rows[g][2 * l]     = a0 + bs[2 * l];
        rows[g][2 * l + 1] = a1 + bs[2 * l + 1];
    }
    __syncthreads();
    if (!act) return;

    const float2* wf2 = reinterpret_cast<const float2*>(w);
    float acc0 = 0.f, acc1 = 0.f;
    #pragma unroll
    for (int k = 0; k < HIDDEN; k++) {
        float rk = rows[g][k];
        float2 wk = wf2[k * 16 + l];
        acc0 += rk * wk.x;
        acc1 += rk * wk.y;
    }
    tout[node * 16 + l] = (unsigned int)f2bf(acc0) | ((unsigned int)f2bf(acc1) << 16);
}

__global__ __launch_bounds__(256) void k_gather_lin3(const unsigned int* __restrict__ tin,
                                                     const int* __restrict__ csr,
                                                     const int* __restrict__ ptr,
                                                     const float* __restrict__ b,
                                                     const float* __restrict__ W,
                                                     float* __restrict__ t3,
                                                     int n) {
    __shared__ float w[HIDDEN * OUT_DIM];
    __shared__ float bs[HIDDEN];
    int tid = threadIdx.x;
    if (tid < HIDDEN * OUT_DIM) w[tid] = W[tid];
    if (tid < HIDDEN) bs[tid] = b[tid];
    __syncthreads();

    int g = tid >> 4;
    int l = tid & 15;
    int node = blockIdx.x * 16 + g;
    if (node >= n) return;

    int start = node ? ptr[node - 1] : 0;
    int end = ptr[node];
    float a0 = 0.f, a1 = 0.f;
    int j = start;
    for (; j + 3 < end; j += 4) {
        int s0 = csr[j], s1 = csr[j + 1], s2 = csr[j + 2], s3 = csr[j + 3];
        unsigned int u0 = tin[s0 * 16 + l];
        unsigned int u1 = tin[s1 * 16 + l];
        unsigned int u2 = tin[s2 * 16 + l];
        unsigned int u3 = tin[s3 * 16 + l];
        a0 += bf2f((unsigned short)(u0 & 0xffffu)) + bf2f((unsigned short)(u1 & 0xffffu));
        a1 += bf2f((unsigned short)(u0 >> 16))     + bf2f((unsigned short)(u1 >> 16));
        a0 += bf2f((unsigned short)(u2 & 0xffffu)) + bf2f((unsigned short)(u3 & 0xffffu));
        a1 += bf2f((unsigned short)(u2 >> 16))     + bf2f((unsigned short)(u3 >> 16));
    }
    for (; j < end; j++) {
        unsigned int u = tin[csr[j] * 16 + l];
        a0 += bf2f((unsigned short)(u & 0xffffu));
        a1 += bf2f((unsigned short)(u >> 16));
    }
    float r0 = a0 + bs[2 * l], r1 = a1 + bs[2 * l + 1];
    float p0 = r0 * w[(2 * l) * 2 + 0] + r1 * w[(2 * l + 1) * 2 + 0];
    float p1 = r0 * w[(2 * l) * 2 + 1] + r1 * w[(2 * l + 1) * 2 + 1];
    #pragma unroll
    for (int off = 1; off < 16; off <<= 1) {
        p0 += __shfl_xor(p0, off);
        p1 += __shfl_xor(p1, off);
    }
    if (l == 0) {
        float2* o = reinterpret_cast<float2*>(t3 + (long long)node * 2);
        *o = make_float2(p0, p1);
    }
}

// ---------------- final gather (2 f32 feats) + bias -> d_out ----------------

__global__ void k_gather2_out(const float* __restrict__ t3,
                              const int* __restrict__ csr,
                              const int* __restrict__ ptr,
                              const float* __restrict__ b3,
                              float* __restrict__ out, int n) {
    int node = blockIdx.x * blockDim.x + threadIdx.x;
    if (node >= n) return;
    int start = node ? ptr[node - 1] : 0;
    int end = ptr[node];
    float a0 = 0.f, a1 = 0.f;
    int j = start;
    for (; j + 1 < end; j += 2) {
        int s0 = csr[j], s1 = csr[j + 1];
        float2 v0 = *reinterpret_cast<const float2*>(t3 + (long long)s0 * 2);
        float2 v1 = *reinterpret_cast<const float2*>(t3 + (long long)s1 * 2);
        a0 += v0.x + v1.x;
        a1 += v0.y + v1.y;
    }
    if (j < end) {
        float2 v = *reinterpret_cast<const float2*>(t3 + (long long)csr[j] * 2);
        a0 += v.x; a1 += v.y;
    }
    float2* o = reinterpret_cast<float2*>(out + (long long)node * 2);
    *o = make_float2(a0 + b3[0], a1 + b3[1]);
}

extern "C" void kernel_launch(void* const* d_in, const int* in_sizes, int n_in,
                              void* d_out, int out_size, void* d_ws, size_t ws_size,
                              hipStream_t stream) {
    const float* nf = (const float*)d_in[0];   // node_feats f32 [N,64]
    const float* W1 = (const float*)d_in[2];   // [64,32]
    const float* b1 = (const float*)d_in[3];   // [32]
    const float* W2 = (const float*)d_in[4];   // [32,32]
    const float* b2 = (const float*)d_in[5];   // [32]
    const float* W3 = (const float*)d_in[6];   // [32,2]
    const float* b3 = (const float*)d_in[7];   // [2]
    const float* Wl = (const float*)d_in[8];   // [64,1]
    const float* bl = (const float*)d_in[9];   // [1]
    const int* src  = (const int*)d_in[10];
    const int* dst  = (const int*)d_in[11];
    const int* gids = (const int*)d_in[12];

    const int N = in_sizes[0] / IN_FEATS;     // 100000
    const int E = in_sizes[10];               // 1600000
    const int nb_sz = (N + NB - 1) / NB;      // 196 (<=256 required for packing)

    float* out = (float*)d_out;

    // workspace layout:
    unsigned int* tA = (unsigned int*)d_ws;                // bf16 table A [N,32] (6.4MB)
    unsigned int* tB = tA + (size_t)N * 16;                // bf16 table B [N,32] (6.4MB)
    float* t3    = (float*)(tB + (size_t)N * 16);          // [N,2] f32 (0.8MB)
    unsigned int* pairs = (unsigned int*)(t3 + (size_t)N * OUT_DIM); // [E] packed (6.4MB)
    int* csr     = (int*)(pairs + E);                      // [E] (6.4MB)
    int* ptr     = csr + E;                                // [N]
    int* gcount  = ptr + N;                                // [NB]
    int* gbase   = gcount + NB;                            // [NB+1]
    int* gcur    = gbase + NB + 1;                         // [NB]
    float* ge    = (float*)(gcur + NB);                    // [64,64]
    int* gstart  = (int*)(ge + N_GRAPHS * IN_FEATS);       // [65]
    int* done    = gstart + N_GRAPHS + 1;                  // [2]

    const int TB = 256;
    int nodeBlocks = (N + TB - 1) / TB;
    int partBlocks = (E + PCH - 1) / PCH;
    int fusedBlocks = (N + 15) / 16;

    // K0: init
    k_init<<<1, TB, 0, stream>>>(gids, N, gstart, ge, gcount, done);

    // K1: fused front-end — hist(+scan) | gsum(+pred) | lin1 run concurrently
    k_front<<<G_HIST + G_GSUM + G_LIN1, TB, 0, stream>>>(
        dst, E, nb_sz, gcount, gbase, gcur,
        nf, gids, gstart, ge, N, Wl, bl, out,
        W1, tA, done);

    // K2/K3: edge partition + per-bucket counting sort -> CSR
    k_partition<<<partBlocks, TB, 0, stream>>>(src, dst, gcur, pairs, E, nb_sz);
    k_csr_local<<<NB, TB, 0, stream>>>(pairs, gbase, csr, ptr, N, nb_sz);

    // K4..K6: GCN chain
    k_gather_lin2<<<fusedBlocks, TB, 0, stream>>>(tA, csr, ptr, b1, W2, tB, N);
    k_gather_lin3<<<fusedBlocks, TB, 0, stream>>>(tB, csr, ptr, b2, W3, t3, N);
    k_gather2_out<<<nodeBlocks, TB, 0, stream>>>(t3, csr, ptr, b3, out + N_GRAPHS, N);
}